// Round 1
// baseline (88.043 us; speedup 1.0000x reference)
//
#include <hip/hip_runtime.h>
#include <math.h>

#define BATCH 16384
#define N0 57
#define NX (N0*N0)      // 3249
#define GPB 4           // matrices per block in k_bilinear
#define HS 5
#define NCLS 17
#define NTRI 15
#define EPSV 1e-4f
#define WCS 8           // padded row stride of Wc
#define WS_Y_OFF 512    // float offset of y region in workspace

// ---------------------------------------------------------------- k_setup
// Wc = W1 @ W2 @ W3  (57x5), stored padded [57][8] at ws[0..456)
__global__ __launch_bounds__(512) void k_setup(const float* __restrict__ W1,
                                               const float* __restrict__ W2,
                                               const float* __restrict__ W3,
                                               float* __restrict__ wc_out) {
    __shared__ float w23[20 * HS];
    int t = threadIdx.x;
    if (t < 20 * HS) {
        int k = t / HS, j = t % HS;
        float acc = 0.f;
        for (int l = 0; l < 10; ++l) acc = fmaf(W2[k * 10 + l], W3[l * HS + j], acc);
        w23[t] = acc;
    }
    __syncthreads();
    if (t < N0 * WCS) {
        int a = t / WCS, j = t % WCS;
        float acc = 0.f;
        if (j < HS) {
            for (int k = 0; k < 20; ++k) acc = fmaf(W1[a * 20 + k], w23[k * HS + j], acc);
        }
        wc_out[t] = acc;   // pads written as 0
    }
}

// ------------------------------------------------------------- k_bilinear
// y = Wc^T x Wc per batch element; store 15 upper-tri values (padded to 16).
__global__ __launch_bounds__(256) void k_bilinear(const float* __restrict__ x,
                                                  const float* __restrict__ wc_in,
                                                  float* __restrict__ y_out) {
    __shared__ float xs[GPB * NX];        // 51984 B
    __shared__ float wcs[N0 * WCS];       // 1824 B
    int tid = threadIdx.x;

    for (int i = tid; i < N0 * WCS; i += 256) wcs[i] = wc_in[i];

    // group of 4 matrices is contiguous + 16B aligned (4*3249*4 % 16 == 0)
    const float4* src = (const float4*)(x + (size_t)blockIdx.x * (GPB * NX));
    float4* dst = (float4*)xs;
    for (int i = tid; i < (GPB * NX) / 4; i += 256) dst[i] = src[i];
    __syncthreads();

    int w = tid >> 6, lane = tid & 63;
    float s[HS]  = {0.f, 0.f, 0.f, 0.f, 0.f};
    float wv[HS] = {0.f, 0.f, 0.f, 0.f, 0.f};
    if (lane < N0) {
        const float* row = &xs[w * NX + lane * N0];
        for (int b = 0; b < N0; ++b) {
            float xv = row[b];
            #pragma unroll
            for (int j = 0; j < HS; ++j) s[j] = fmaf(xv, wcs[b * WCS + j], s[j]);
        }
        #pragma unroll
        for (int i = 0; i < HS; ++i) wv[i] = wcs[lane * WCS + i];
    }

    // upper-tri outer product partials, then wave reduction
    float p[NTRI];
    int t = 0;
    #pragma unroll
    for (int i = 0; i < HS; ++i)
        #pragma unroll
        for (int j = i; j < HS; ++j) p[t++] = wv[i] * s[j];

    #pragma unroll
    for (int k = 0; k < NTRI; ++k) {
        #pragma unroll
        for (int msk = 32; msk >= 1; msk >>= 1) p[k] += __shfl_xor(p[k], msk, 64);
    }

    if (lane == 0) {
        float4* o = (float4*)&y_out[(size_t)(blockIdx.x * GPB + w) * 16];
        o[0] = make_float4(p[0],  p[1],  p[2],  p[3]);
        o[1] = make_float4(p[4],  p[5],  p[6],  p[7]);
        o[2] = make_float4(p[8],  p[9],  p[10], p[11]);
        o[3] = make_float4(p[12], p[13], p[14], 0.f);
    }
}

// ------------------------------------------------------------------ k_eig
// One thread per matrix: 5x5 Jacobi eigensolve -> logm -> tri -> linear.
__global__ __launch_bounds__(256) void k_eig(const float* __restrict__ y_in,
                                             const float* __restrict__ lin_w,
                                             const float* __restrict__ lin_b,
                                             float* __restrict__ out) {
    __shared__ float lws[NCLS * NTRI];
    __shared__ float lbs[NCLS];
    int tid = threadIdx.x;
    if (tid < NCLS * NTRI) lws[tid] = lin_w[tid];
    if (tid < NCLS) lbs[tid] = lin_b[tid];
    __syncthreads();

    int m = blockIdx.x * 256 + tid;
    const float4* yin = (const float4*)&y_in[(size_t)m * 16];
    float4 q0 = yin[0], q1 = yin[1], q2 = yin[2], q3 = yin[3];
    float tri[16] = {q0.x, q0.y, q0.z, q0.w, q1.x, q1.y, q1.z, q1.w,
                     q2.x, q2.y, q2.z, q2.w, q3.x, q3.y, q3.z, q3.w};

    float A[HS][HS], V[HS][HS];
    int t = 0;
    #pragma unroll
    for (int i = 0; i < HS; ++i)
        #pragma unroll
        for (int j = i; j < HS; ++j) { A[i][j] = tri[t]; A[j][i] = tri[t]; ++t; }
    #pragma unroll
    for (int i = 0; i < HS; ++i)
        #pragma unroll
        for (int j = 0; j < HS; ++j) V[i][j] = (i == j) ? 1.f : 0.f;

    // cyclic Jacobi, 6 sweeps, fully unrolled (all indices compile-time)
    #pragma unroll
    for (int sweep = 0; sweep < 6; ++sweep) {
        #pragma unroll
        for (int p = 0; p < HS - 1; ++p) {
            #pragma unroll
            for (int q = p + 1; q < HS; ++q) {
                float apq = A[p][q];
                float app = A[p][p], aqq = A[q][q];
                bool nz = fabsf(apq) > 1e-30f;
                float denom = nz ? 2.f * apq : 1.f;
                float tau = (aqq - app) / denom;
                float tt = 1.f / (fabsf(tau) + sqrtf(fmaf(tau, tau, 1.f)));
                tt = copysignf(tt, tau);
                tt = nz ? tt : 0.f;
                float c = rsqrtf(fmaf(tt, tt, 1.f));
                float sn = tt * c;
                #pragma unroll
                for (int k = 0; k < HS; ++k) {      // A = A * J
                    float akp = A[k][p], akq = A[k][q];
                    A[k][p] = fmaf(c, akp, -sn * akq);
                    A[k][q] = fmaf(sn, akp,  c * akq);
                }
                #pragma unroll
                for (int k = 0; k < HS; ++k) {      // A = J^T * A
                    float apk = A[p][k], aqk = A[q][k];
                    A[p][k] = fmaf(c, apk, -sn * aqk);
                    A[q][k] = fmaf(sn, apk,  c * aqk);
                }
                #pragma unroll
                for (int k = 0; k < HS; ++k) {      // V = V * J
                    float vkp = V[k][p], vkq = V[k][q];
                    V[k][p] = fmaf(c, vkp, -sn * vkq);
                    V[k][q] = fmaf(sn, vkp,  c * vkq);
                }
            }
        }
    }

    float lwv[HS];
    #pragma unroll
    for (int i = 0; i < HS; ++i) lwv[i] = logf(fmaxf(A[i][i], EPSV));

    // tri of logm = V diag(lwv) V^T
    float tri2[NTRI];
    t = 0;
    #pragma unroll
    for (int i = 0; i < HS; ++i) {
        float vi[HS];
        #pragma unroll
        for (int k = 0; k < HS; ++k) vi[k] = V[i][k] * lwv[k];
        #pragma unroll
        for (int j = i; j < HS; ++j) {
            float acc = 0.f;
            #pragma unroll
            for (int k = 0; k < HS; ++k) acc = fmaf(vi[k], V[j][k], acc);
            tri2[t++] = acc;
        }
    }

    // linear 15 -> 17
    #pragma unroll
    for (int c = 0; c < NCLS; ++c) {
        float acc = lbs[c];
        #pragma unroll
        for (int k = 0; k < NTRI; ++k) acc = fmaf(tri2[k], lws[c * NTRI + k], acc);
        out[(size_t)m * NCLS + c] = acc;
    }
}

// ----------------------------------------------------------------- launch
extern "C" void kernel_launch(void* const* d_in, const int* in_sizes, int n_in,
                              void* d_out, int out_size, void* d_ws, size_t ws_size,
                              hipStream_t stream) {
    const float* x     = (const float*)d_in[0];
    const float* W1    = (const float*)d_in[1];
    const float* W2    = (const float*)d_in[2];
    const float* W3    = (const float*)d_in[3];
    const float* lin_w = (const float*)d_in[4];
    const float* lin_b = (const float*)d_in[5];
    float* out = (float*)d_out;
    float* ws  = (float*)d_ws;
    float* wc  = ws;                 // 456 floats (57x8 padded)
    float* y   = ws + WS_Y_OFF;      // 16384*16 floats

    k_setup<<<1, 512, 0, stream>>>(W1, W2, W3, wc);
    k_bilinear<<<BATCH / GPB, 256, 0, stream>>>(x, wc, y);
    k_eig<<<BATCH / 256, 256, 0, stream>>>(y, lin_w, lin_b, out);
}

// Round 2
// 58.521 us; speedup vs baseline: 1.5045x; 1.5045x over previous
//
#include <hip/hip_runtime.h>
#include <math.h>

#define BATCH 16384
#define N0 57
#define NX 3249          // 57*57
#define GPB 4            // matrices per block
#define HS 5
#define NCLS 17
#define NTRI 15
#define EPSV 1e-4f

// ---------------------------------------------------------------- helpers
template<int CTRL>
__device__ __forceinline__ float dpp_mov0(float x) {
    // old=0, row_mask=0xF, bank_mask=0xF, bound_ctrl=true (invalid lanes -> 0)
    return __int_as_float(__builtin_amdgcn_update_dpp(
        0, __float_as_int(x), CTRL, 0xF, 0xF, true));
}
// full 64-lane sum, result valid in lane 63, pure VALU (no LDS pipe)
__device__ __forceinline__ float wave_sum64(float x) {
    x += dpp_mov0<0x111>(x);   // row_shr:1
    x += dpp_mov0<0x112>(x);   // row_shr:2
    x += dpp_mov0<0x114>(x);   // row_shr:4
    x += dpp_mov0<0x118>(x);   // row_shr:8  -> lane15 of each row = row sum
    x += dpp_mov0<0x142>(x);   // row_bcast:15
    x += dpp_mov0<0x143>(x);   // row_bcast:31 -> lane 63 = total
    return x;
}

__device__ __forceinline__ void load_lds16(const float* g, float* l) {
    __builtin_amdgcn_global_load_lds(
        (const __attribute__((address_space(1))) void*)g,
        (__attribute__((address_space(3))) void*)l, 16, 0, 0);
}

// ----------------------------------------------------------------- k_main
// Fused: Wc = W1@W2@W3 (per block, hidden under staging) + y = Wc^T x Wc.
__global__ __launch_bounds__(256) void k_main(const float* __restrict__ x,
                                              const float* __restrict__ W1,
                                              const float* __restrict__ W2,
                                              const float* __restrict__ W3,
                                              float* __restrict__ y_out) {
    __shared__ float xs[13312];     // 3328 16B-slots = 53248 B (3249 used + pad)
    __shared__ float wcsT[304];     // Wc transposed, rows padded to 60 cols
    __shared__ float w23[100];      // W2@W3 (20x5)
    const int tid  = threadIdx.x;
    const int lane = tid & 63;
    const int wave = tid >> 6;

    // (1) W-matrix loads into registers FIRST (oldest vmcnt entries, so the
    //     auto-wait for them does NOT drain the staging queue issued below).
    float w2r[10], w3c[10], w1r[20];
    const int kk = tid / 5, jj = tid % 5;
    if (tid < 100) {
        #pragma unroll
        for (int l = 0; l < 10; ++l) { w2r[l] = W2[kk * 10 + l]; w3c[l] = W3[l * HS + jj]; }
    }
    if (tid < N0) {
        const float4* w1p = (const float4*)(W1 + tid * 20);   // 80 B rows, 16B aligned
        #pragma unroll
        for (int q = 0; q < 5; ++q) {
            float4 v = w1p[q];
            w1r[4*q] = v.x; w1r[4*q+1] = v.y; w1r[4*q+2] = v.z; w1r[4*q+3] = v.w;
        }
    }
    if (tid < 304) wcsT[tid] = 0.f;   // zero pads (cols 57..59 and tail)

    // (2) async staging: 4 packed matrices (51984 B), linear dest, width 16
    const float* gbase = x + (size_t)blockIdx.x * (GPB * NX);
    #pragma unroll
    for (int r = 0; r < 13; ++r) {
        int slot = r * 256 + tid;
        int cs = slot > 3248 ? 3248 : slot;            // clamp: dup load into pad
        load_lds16(gbase + (size_t)cs * 4, &xs[r * 1024 + (tid & 192) * 4]);
    }

    // (3) w23 = W2@W3 (register inputs; waits only W-loads, staging stays in flight)
    if (tid < 100) {
        float acc = 0.f;
        #pragma unroll
        for (int l = 0; l < 10; ++l) acc = fmaf(w2r[l], w3c[l], acc);
        w23[tid] = acc;
    }
    asm volatile("s_waitcnt lgkmcnt(0)" ::: "memory");   // LDS writes only, NOT vmcnt
    __builtin_amdgcn_s_barrier();

    // (4) Wc rows -> wcsT (transposed, stride 60)
    if (tid < N0) {
        #pragma unroll
        for (int j = 0; j < HS; ++j) {
            float acc = 0.f;
            #pragma unroll
            for (int k = 0; k < 20; ++k) acc = fmaf(w1r[k], w23[k * HS + j], acc);
            wcsT[j * 60 + tid] = acc;
        }
    }

    // (5) main barrier: staging + wcsT complete
    asm volatile("s_waitcnt vmcnt(0) lgkmcnt(0)" ::: "memory");
    __builtin_amdgcn_s_barrier();

    // (6) compute: wave w handles matrix w; lane a owns row a
    const int la = (lane < N0) ? lane : 56;
    const float* row = &xs[wave * NX + la * N0];
    float wv[HS];
    #pragma unroll
    for (int j = 0; j < HS; ++j) {
        float v = wcsT[j * 60 + lane];     // lane>=57 reads pad/garbage, masked:
        wv[j] = (lane < N0) ? v : 0.f;
    }
    float s[HS] = {0.f, 0.f, 0.f, 0.f, 0.f};
    #pragma unroll
    for (int c = 0; c < 14; ++c) {         // b = 4c..4c+3 (0..55)
        float r0 = row[4*c], r1 = row[4*c+1], r2 = row[4*c+2], r3 = row[4*c+3];
        #pragma unroll
        for (int j = 0; j < HS; ++j) {
            float4 w4 = *(const float4*)&wcsT[j * 60 + 4 * c];   // uniform b128
            s[j] = fmaf(r0, w4.x, fmaf(r1, w4.y, fmaf(r2, w4.z, fmaf(r3, w4.w, s[j]))));
        }
    }
    {   // tail b = 56
        float r56 = row[56];
        #pragma unroll
        for (int j = 0; j < HS; ++j) s[j] = fmaf(r56, wcsT[j * 60 + 56], s[j]);
    }

    // (7) upper-tri outer product + DPP reduction (VALU only)
    float p[NTRI];
    int t = 0;
    #pragma unroll
    for (int i = 0; i < HS; ++i)
        #pragma unroll
        for (int j = i; j < HS; ++j) { p[t] = wave_sum64(wv[i] * s[j]); ++t; }

    if (lane == 63) {
        float4* o = (float4*)&y_out[(size_t)(blockIdx.x * GPB + wave) * 16];
        o[0] = make_float4(p[0],  p[1],  p[2],  p[3]);
        o[1] = make_float4(p[4],  p[5],  p[6],  p[7]);
        o[2] = make_float4(p[8],  p[9],  p[10], p[11]);
        o[3] = make_float4(p[12], p[13], p[14], 0.f);
    }
}

// ------------------------------------------------------------------ k_eig
// One thread per matrix: 5x5 Jacobi eigensolve -> logm -> tri -> linear.
__global__ __launch_bounds__(256) void k_eig(const float* __restrict__ y_in,
                                             const float* __restrict__ lin_w,
                                             const float* __restrict__ lin_b,
                                             float* __restrict__ out) {
    __shared__ float lws[NCLS * NTRI];
    __shared__ float lbs[NCLS];
    int tid = threadIdx.x;
    if (tid < NCLS * NTRI) lws[tid] = lin_w[tid];
    if (tid < NCLS) lbs[tid] = lin_b[tid];
    __syncthreads();

    int m = blockIdx.x * 256 + tid;
    const float4* yin = (const float4*)&y_in[(size_t)m * 16];
    float4 q0 = yin[0], q1 = yin[1], q2 = yin[2], q3 = yin[3];
    float tri[16] = {q0.x, q0.y, q0.z, q0.w, q1.x, q1.y, q1.z, q1.w,
                     q2.x, q2.y, q2.z, q2.w, q3.x, q3.y, q3.z, q3.w};

    float A[HS][HS], V[HS][HS];
    int t = 0;
    #pragma unroll
    for (int i = 0; i < HS; ++i)
        #pragma unroll
        for (int j = i; j < HS; ++j) { A[i][j] = tri[t]; A[j][i] = tri[t]; ++t; }
    #pragma unroll
    for (int i = 0; i < HS; ++i)
        #pragma unroll
        for (int j = 0; j < HS; ++j) V[i][j] = (i == j) ? 1.f : 0.f;

    #pragma unroll
    for (int sweep = 0; sweep < 6; ++sweep) {
        #pragma unroll
        for (int p = 0; p < HS - 1; ++p) {
            #pragma unroll
            for (int q = p + 1; q < HS; ++q) {
                float apq = A[p][q];
                float app = A[p][p], aqq = A[q][q];
                bool nz = fabsf(apq) > 1e-30f;
                float denom = nz ? 2.f * apq : 1.f;
                float tau = (aqq - app) / denom;
                float tt = 1.f / (fabsf(tau) + sqrtf(fmaf(tau, tau, 1.f)));
                tt = copysignf(tt, tau);
                tt = nz ? tt : 0.f;
                float c = rsqrtf(fmaf(tt, tt, 1.f));
                float sn = tt * c;
                #pragma unroll
                for (int k = 0; k < HS; ++k) {
                    float akp = A[k][p], akq = A[k][q];
                    A[k][p] = fmaf(c, akp, -sn * akq);
                    A[k][q] = fmaf(sn, akp,  c * akq);
                }
                #pragma unroll
                for (int k = 0; k < HS; ++k) {
                    float apk = A[p][k], aqk = A[q][k];
                    A[p][k] = fmaf(c, apk, -sn * aqk);
                    A[q][k] = fmaf(sn, apk,  c * aqk);
                }
                #pragma unroll
                for (int k = 0; k < HS; ++k) {
                    float vkp = V[k][p], vkq = V[k][q];
                    V[k][p] = fmaf(c, vkp, -sn * vkq);
                    V[k][q] = fmaf(sn, vkp,  c * vkq);
                }
            }
        }
    }

    float lwv[HS];
    #pragma unroll
    for (int i = 0; i < HS; ++i) lwv[i] = logf(fmaxf(A[i][i], EPSV));

    float tri2[NTRI];
    t = 0;
    #pragma unroll
    for (int i = 0; i < HS; ++i) {
        float vi[HS];
        #pragma unroll
        for (int k = 0; k < HS; ++k) vi[k] = V[i][k] * lwv[k];
        #pragma unroll
        for (int j = i; j < HS; ++j) {
            float acc = 0.f;
            #pragma unroll
            for (int k = 0; k < HS; ++k) acc = fmaf(vi[k], V[j][k], acc);
            tri2[t++] = acc;
        }
    }

    #pragma unroll
    for (int c = 0; c < NCLS; ++c) {
        float acc = lbs[c];
        #pragma unroll
        for (int k = 0; k < NTRI; ++k) acc = fmaf(tri2[k], lws[c * NTRI + k], acc);
        out[(size_t)m * NCLS + c] = acc;
    }
}

// ----------------------------------------------------------------- launch
extern "C" void kernel_launch(void* const* d_in, const int* in_sizes, int n_in,
                              void* d_out, int out_size, void* d_ws, size_t ws_size,
                              hipStream_t stream) {
    const float* x     = (const float*)d_in[0];
    const float* W1    = (const float*)d_in[1];
    const float* W2    = (const float*)d_in[2];
    const float* W3    = (const float*)d_in[3];
    const float* lin_w = (const float*)d_in[4];
    const float* lin_b = (const float*)d_in[5];
    float* out = (float*)d_out;
    float* y   = (float*)d_ws;     // 16384*16 floats

    k_main<<<BATCH / GPB, 256, 0, stream>>>(x, W1, W2, W3, y);
    k_eig<<<BATCH / 256, 256, 0, stream>>>(y, lin_w, lin_b, out);
}

// Round 3
// 58.350 us; speedup vs baseline: 1.5089x; 1.0029x over previous
//
#include <hip/hip_runtime.h>
#include <math.h>

#define BATCH 16384
#define N0 57
#define NX 3249          // 57*57
#define GPB 4            // matrices per block
#define HS 5
#define NCLS 17
#define NTRI 15
#define EPSV 1e-4f

// ---------------------------------------------------------------- helpers
template<int CTRL>
__device__ __forceinline__ float dpp_mov0(float x) {
    // old=0, row_mask=0xF, bank_mask=0xF, bound_ctrl=true (invalid lanes -> 0)
    return __int_as_float(__builtin_amdgcn_update_dpp(
        0, __float_as_int(x), CTRL, 0xF, 0xF, true));
}
// full 64-lane sum, result valid in lane 63, pure VALU (no LDS pipe)
__device__ __forceinline__ float wave_sum64(float x) {
    x += dpp_mov0<0x111>(x);   // row_shr:1
    x += dpp_mov0<0x112>(x);   // row_shr:2
    x += dpp_mov0<0x114>(x);   // row_shr:4
    x += dpp_mov0<0x118>(x);   // row_shr:8
    x += dpp_mov0<0x142>(x);   // row_bcast:15
    x += dpp_mov0<0x143>(x);   // row_bcast:31 -> lane 63 = total
    return x;
}

__device__ __forceinline__ void load_lds16(const float* g, float* l) {
    __builtin_amdgcn_global_load_lds(
        (const __attribute__((address_space(1))) void*)g,
        (__attribute__((address_space(3))) void*)l, 16, 0, 0);
}

// ---------------------------------------------------------------- k_setup
// wc[57][8] = W1@W2@W3, rows padded to 8 (32B-aligned rows)
__global__ __launch_bounds__(128) void k_setup(const float* __restrict__ W1,
                                               const float* __restrict__ W2,
                                               const float* __restrict__ W3,
                                               float* __restrict__ wc_out) {
    __shared__ float w23[100];
    int t = threadIdx.x;
    if (t < 100) {
        int k = t / 5, j = t % 5;
        float acc = 0.f;
        for (int l = 0; l < 10; ++l) acc = fmaf(W2[k * 10 + l], W3[l * 5 + j], acc);
        w23[t] = acc;
    }
    __syncthreads();
    if (t < N0) {
        float r[5];
        #pragma unroll
        for (int j = 0; j < 5; ++j) {
            float acc = 0.f;
            for (int k = 0; k < 20; ++k) acc = fmaf(W1[t * 20 + k], w23[k * 5 + j], acc);
            r[j] = acc;
        }
        float4* o = (float4*)&wc_out[t * 8];
        o[0] = make_float4(r[0], r[1], r[2], r[3]);
        o[1] = make_float4(r[4], 0.f, 0.f, 0.f);
    }
}

// ----------------------------------------------------------------- k_main
// y = Wc^T x Wc per matrix. Column scheme (x symmetric): lane a owns col a,
// s[j](a) = sum_b x[b][a] * wc[b][j]; wc comes from SGPRs (s_load), x from
// conflict-free lane-consecutive LDS reads.
__global__ __launch_bounds__(256) void k_main(const float* __restrict__ x,
                                              const float* __restrict__ wc,
                                              float* __restrict__ y_out) {
    __shared__ float xs[13312];     // 3328 16B-slots = 53248 B
    const int tid  = threadIdx.x;
    const int lane = tid & 63;
    const int wave = tid >> 6;

    // per-lane Wc row for the left multiply (vector loads, L2-hit, issue first)
    float wv[HS];
    {
        int a = (lane < N0) ? lane : 0;
        const float4* wp = (const float4*)&wc[a * 8];
        float4 v0 = wp[0];
        float  v4 = wc[a * 8 + 4];
        wv[0] = v0.x; wv[1] = v0.y; wv[2] = v0.z; wv[3] = v0.w; wv[4] = v4;
        if (lane >= N0) { wv[0] = wv[1] = wv[2] = wv[3] = wv[4] = 0.f; }
    }

    // async staging: 4 packed matrices (51984 B), linear dest, width 16
    const float* gbase = x + (size_t)blockIdx.x * (GPB * NX);
    #pragma unroll
    for (int r = 0; r < 13; ++r) {
        int slot = r * 256 + tid;
        int cs = slot > 3248 ? 3248 : slot;            // clamp: dup load into pad
        load_lds16(gbase + (size_t)cs * 4, &xs[r * 1024 + (tid & 192) * 4]);
    }

    asm volatile("s_waitcnt vmcnt(0)" ::: "memory");
    __builtin_amdgcn_s_barrier();

    // compute: wave w -> matrix w; lane a -> column a
    const float* base = &xs[wave * NX];
    float s[HS] = {0.f, 0.f, 0.f, 0.f, 0.f};
    #pragma unroll
    for (int b = 0; b < N0; ++b) {
        float xv = base[b * N0 + lane];     // lanes>=57 read in-bounds garbage
        #pragma unroll
        for (int j = 0; j < HS; ++j) s[j] = fmaf(xv, wc[b * 8 + j], s[j]);  // s_load
    }

    // upper-tri outer product + DPP reduction (VALU only)
    float p[NTRI];
    int t = 0;
    #pragma unroll
    for (int i = 0; i < HS; ++i)
        #pragma unroll
        for (int j = i; j < HS; ++j) { p[t] = wave_sum64(wv[i] * s[j]); ++t; }

    if (lane == 63) {
        float4* o = (float4*)&y_out[(size_t)(blockIdx.x * GPB + wave) * 16];
        o[0] = make_float4(p[0],  p[1],  p[2],  p[3]);
        o[1] = make_float4(p[4],  p[5],  p[6],  p[7]);
        o[2] = make_float4(p[8],  p[9],  p[10], p[11]);
        o[3] = make_float4(p[12], p[13], p[14], 0.f);
    }
}

// ------------------------------------------------------------------ k_eig
// One thread per matrix: 5x5 Jacobi eigensolve -> logm -> tri -> linear.
// 64-thread blocks so all 256 CUs get work.
__global__ __launch_bounds__(64) void k_eig(const float* __restrict__ y_in,
                                            const float* __restrict__ lin_w,
                                            const float* __restrict__ lin_b,
                                            float* __restrict__ out) {
    __shared__ float lws[NCLS * NTRI];
    __shared__ float lbs[NCLS];
    int tid = threadIdx.x;
    for (int i = tid; i < NCLS * NTRI; i += 64) lws[i] = lin_w[i];
    if (tid < NCLS) lbs[tid] = lin_b[tid];
    __syncthreads();

    int m = blockIdx.x * 64 + tid;
    const float4* yin = (const float4*)&y_in[(size_t)m * 16];
    float4 q0 = yin[0], q1 = yin[1], q2 = yin[2], q3 = yin[3];
    float tri[16] = {q0.x, q0.y, q0.z, q0.w, q1.x, q1.y, q1.z, q1.w,
                     q2.x, q2.y, q2.z, q2.w, q3.x, q3.y, q3.z, q3.w};

    float A[HS][HS], V[HS][HS];
    int t = 0;
    #pragma unroll
    for (int i = 0; i < HS; ++i)
        #pragma unroll
        for (int j = i; j < HS; ++j) { A[i][j] = tri[t]; A[j][i] = tri[t]; ++t; }
    #pragma unroll
    for (int i = 0; i < HS; ++i)
        #pragma unroll
        for (int j = 0; j < HS; ++j) V[i][j] = (i == j) ? 1.f : 0.f;

    #pragma unroll
    for (int sweep = 0; sweep < 6; ++sweep) {
        #pragma unroll
        for (int p = 0; p < HS - 1; ++p) {
            #pragma unroll
            for (int q = p + 1; q < HS; ++q) {
                float apq = A[p][q];
                float app = A[p][p], aqq = A[q][q];
                bool nz = fabsf(apq) > 1e-30f;
                float denom = nz ? 2.f * apq : 1.f;
                float tau = (aqq - app) / denom;
                float tt = 1.f / (fabsf(tau) + sqrtf(fmaf(tau, tau, 1.f)));
                tt = copysignf(tt, tau);
                tt = nz ? tt : 0.f;
                float c = rsqrtf(fmaf(tt, tt, 1.f));
                float sn = tt * c;
                #pragma unroll
                for (int k = 0; k < HS; ++k) {
                    float akp = A[k][p], akq = A[k][q];
                    A[k][p] = fmaf(c, akp, -sn * akq);
                    A[k][q] = fmaf(sn, akp,  c * akq);
                }
                #pragma unroll
                for (int k = 0; k < HS; ++k) {
                    float apk = A[p][k], aqk = A[q][k];
                    A[p][k] = fmaf(c, apk, -sn * aqk);
                    A[q][k] = fmaf(sn, apk,  c * aqk);
                }
                #pragma unroll
                for (int k = 0; k < HS; ++k) {
                    float vkp = V[k][p], vkq = V[k][q];
                    V[k][p] = fmaf(c, vkp, -sn * vkq);
                    V[k][q] = fmaf(sn, vkp,  c * vkq);
                }
            }
        }
    }

    float lwv[HS];
    #pragma unroll
    for (int i = 0; i < HS; ++i) lwv[i] = logf(fmaxf(A[i][i], EPSV));

    float tri2[NTRI];
    t = 0;
    #pragma unroll
    for (int i = 0; i < HS; ++i) {
        float vi[HS];
        #pragma unroll
        for (int k = 0; k < HS; ++k) vi[k] = V[i][k] * lwv[k];
        #pragma unroll
        for (int j = i; j < HS; ++j) {
            float acc = 0.f;
            #pragma unroll
            for (int k = 0; k < HS; ++k) acc = fmaf(vi[k], V[j][k], acc);
            tri2[t++] = acc;
        }
    }

    #pragma unroll
    for (int c = 0; c < NCLS; ++c) {
        float acc = lbs[c];
        #pragma unroll
        for (int k = 0; k < NTRI; ++k) acc = fmaf(tri2[k], lws[c * NTRI + k], acc);
        out[(size_t)m * NCLS + c] = acc;
    }
}

// ----------------------------------------------------------------- launch
extern "C" void kernel_launch(void* const* d_in, const int* in_sizes, int n_in,
                              void* d_out, int out_size, void* d_ws, size_t ws_size,
                              hipStream_t stream) {
    const float* x     = (const float*)d_in[0];
    const float* W1    = (const float*)d_in[1];
    const float* W2    = (const float*)d_in[2];
    const float* W3    = (const float*)d_in[3];
    const float* lin_w = (const float*)d_in[4];
    const float* lin_b = (const float*)d_in[5];
    float* out = (float*)d_out;
    float* ws  = (float*)d_ws;
    float* wc  = ws;               // 456 floats, padded [57][8]
    float* y   = ws + 512;         // 16384*16 floats

    k_setup<<<1, 128, 0, stream>>>(W1, W2, W3, wc);
    k_main<<<BATCH / GPB, 256, 0, stream>>>(x, wc, y);
    k_eig<<<BATCH / 64, 64, 0, stream>>>(y, lin_w, lin_b, out);
}